// Round 1
// baseline (2974.654 us; speedup 1.0000x reference)
//
#include <hip/hip_runtime.h>
#include <cstdint>

#define NNODES 10000
#define NEDGES 320000

typedef unsigned short u16;
typedef unsigned int u32;

__device__ __forceinline__ float siluf(float x) {
    return __fdividef(x, 1.0f + __expf(-x));
}
__device__ __forceinline__ u16 f2bf(float x) {
    union { float f; u32 u; } v; v.f = x;
    u32 r = (v.u + 0x7FFFu + ((v.u >> 16) & 1u)) >> 16;
    return (u16)r;
}
__device__ __forceinline__ float bf2f(u16 b) {
    union { u32 u; float f; } v; v.u = ((u32)b) << 16;
    return v.f;
}

// acc[j] += x.{x,y,z,w} * w[row 0..3][j], row stride == JN
template <int JN>
__device__ __forceinline__ void fma4(const float4 x, const float* __restrict__ w,
                                     float* acc) {
#pragma unroll
    for (int j = 0; j < JN; ++j) {
        float s = fmaf(x.x, w[j], acc[j]);
        s = fmaf(x.y, w[JN + j], s);
        s = fmaf(x.z, w[2 * JN + j], s);
        acc[j] = fmaf(x.w, w[3 * JN + j], s);
    }
}

template <int JN>
__device__ __forceinline__ void fma1(const float x, const float* __restrict__ w,
                                     float* acc) {
#pragma unroll
    for (int j = 0; j < JN; ++j) acc[j] = fmaf(x, w[j], acc[j]);
}

// One thread = one edge. Activations bounce through per-thread LDS columns
// (dynamic k-index must not hit register arrays). 64-thread blocks = 1 wave,
// no __syncthreads needed (each thread touches only its own column t).
__global__ __launch_bounds__(64, 2)
void edge_kernel(const float* __restrict__ h, const float* __restrict__ coord,
                 const float* __restrict__ edge_attr,
                 const int* __restrict__ row, const int* __restrict__ col,
                 const float* __restrict__ ew1, const float* __restrict__ eb1,
                 const float* __restrict__ ew2, const float* __restrict__ eb2,
                 const float* __restrict__ ew3, const float* __restrict__ eb3,
                 const float* __restrict__ cw1, const float* __restrict__ cb1,
                 const float* __restrict__ cw2, const float* __restrict__ cb2,
                 const float* __restrict__ cw3,
                 float* __restrict__ agg_feat, float* __restrict__ agg_c,
                 float* __restrict__ cnt) {
    __shared__ u16 ldsA[128 * 64];  // f1 (j<64), later edge_feat (j<128)
    __shared__ u16 ldsB[128 * 64];  // f2 (j<128), later c1 (j<64)
    const int t = threadIdx.x;
    const int e = blockIdx.x * 64 + t;  // NEDGES % 64 == 0

    const int r = row[e];
    const int c = col[e];
    const float* hr = h + (size_t)r * 128;
    const float* hc = h + (size_t)c * 128;
    const float dx = coord[3 * r + 0] - coord[3 * c + 0];
    const float dy = coord[3 * r + 1] - coord[3 * c + 1];
    const float dz = coord[3 * r + 2] - coord[3 * c + 2];
    const float radial = dx * dx + dy * dy + dz * dz;

    // ---- edge MLP layer 1: 273 -> 64
    float a1[64];
#pragma unroll
    for (int j = 0; j < 64; ++j) a1[j] = eb1[j];
    for (int k = 0; k < 128; k += 4) {
        const float4 x = *(const float4*)(hr + k);
        fma4<64>(x, ew1 + (size_t)k * 64, a1);
    }
    for (int k = 0; k < 128; k += 4) {
        const float4 x = *(const float4*)(hc + k);
        fma4<64>(x, ew1 + (size_t)(128 + k) * 64, a1);
    }
    fma1<64>(radial, ew1 + (size_t)256 * 64, a1);
    {
        const float* ea = edge_attr + (size_t)e * 16;
        for (int k = 0; k < 16; k += 4) {
            const float4 x = *(const float4*)(ea + k);
            fma4<64>(x, ew1 + (size_t)(257 + k) * 64, a1);
        }
    }
#pragma unroll
    for (int j = 0; j < 64; ++j) ldsA[j * 64 + t] = f2bf(siluf(a1[j]));

    // ---- edge MLP layer 2: 64 -> 128
    float a2[128];
#pragma unroll
    for (int j = 0; j < 128; ++j) a2[j] = eb2[j];
    for (int k = 0; k < 64; ++k) {
        const float x = bf2f(ldsA[k * 64 + t]);
        fma1<128>(x, ew2 + (size_t)k * 128, a2);
    }
#pragma unroll
    for (int j = 0; j < 128; ++j) ldsB[j * 64 + t] = f2bf(siluf(a2[j]));

    // ---- edge MLP layer 3: 128 -> 128 = edge_feat; aggregate + stash
    float a3[128];
#pragma unroll
    for (int j = 0; j < 128; ++j) a3[j] = eb3[j];
    for (int k = 0; k < 128; ++k) {
        const float x = bf2f(ldsB[k * 64 + t]);
        fma1<128>(x, ew3 + (size_t)k * 128, a3);
    }
    float* af = agg_feat + (size_t)r * 128;
#pragma unroll
    for (int j = 0; j < 128; ++j) {
        const float v = siluf(a3[j]);
        ldsA[j * 64 + t] = f2bf(v);
        unsafeAtomicAdd(af + j, v);
    }

    // ---- coord MLP layer 1: 128 -> 64
    float b1[64];
#pragma unroll
    for (int j = 0; j < 64; ++j) b1[j] = cb1[j];
    for (int k = 0; k < 128; ++k) {
        const float x = bf2f(ldsA[k * 64 + t]);
        fma1<64>(x, cw1 + (size_t)k * 64, b1);
    }
#pragma unroll
    for (int j = 0; j < 64; ++j) ldsB[j * 64 + t] = f2bf(siluf(b1[j]));

    // ---- coord MLP layer 2 (64 -> 128) fused with cw3 dot (128 -> 1)
    float b2[128];
#pragma unroll
    for (int j = 0; j < 128; ++j) b2[j] = cb2[j];
    for (int k = 0; k < 64; ++k) {
        const float x = bf2f(ldsB[k * 64 + t]);
        fma1<128>(x, cw2 + (size_t)k * 128, b2);
    }
    float cv = 0.0f;
#pragma unroll
    for (int j = 0; j < 128; ++j) cv = fmaf(siluf(b2[j]), cw3[j], cv);

    const float tx = fminf(fmaxf(dx * cv, -100.0f), 100.0f);
    const float ty = fminf(fmaxf(dy * cv, -100.0f), 100.0f);
    const float tz = fminf(fmaxf(dz * cv, -100.0f), 100.0f);
    unsafeAtomicAdd(agg_c + 3 * r + 0, tx);
    unsafeAtomicAdd(agg_c + 3 * r + 1, ty);
    unsafeAtomicAdd(agg_c + 3 * r + 2, tz);
    unsafeAtomicAdd(cnt + r, 1.0f);
}

__global__ __launch_bounds__(64, 2)
void node_kernel(const float* __restrict__ h, const float* __restrict__ coord,
                 const float* __restrict__ nw1, const float* __restrict__ nb1,
                 const float* __restrict__ nw2, const float* __restrict__ nb2,
                 const float* __restrict__ nw3, const float* __restrict__ nb3,
                 const float* __restrict__ agg_feat,
                 const float* __restrict__ agg_c, const float* __restrict__ cnt,
                 float* __restrict__ out_h, float* __restrict__ out_coord) {
    __shared__ u16 lds1[64 * 64];
    __shared__ u16 lds2[128 * 64];
    const int t = threadIdx.x;
    const int n = blockIdx.x * 64 + t;
    if (n >= NNODES) return;
    const float* hn = h + (size_t)n * 128;
    const float* an = agg_feat + (size_t)n * 128;

    // node MLP layer 1: [h, agg] (256) -> 64
    float a1[64];
#pragma unroll
    for (int j = 0; j < 64; ++j) a1[j] = nb1[j];
    for (int k = 0; k < 128; k += 4) {
        const float4 x = *(const float4*)(hn + k);
        fma4<64>(x, nw1 + (size_t)k * 64, a1);
    }
    for (int k = 0; k < 128; k += 4) {
        const float4 x = *(const float4*)(an + k);
        fma4<64>(x, nw1 + (size_t)(128 + k) * 64, a1);
    }
#pragma unroll
    for (int j = 0; j < 64; ++j) lds1[j * 64 + t] = f2bf(siluf(a1[j]));

    // node MLP layer 2: 64 -> 128
    float a2[128];
#pragma unroll
    for (int j = 0; j < 128; ++j) a2[j] = nb2[j];
    for (int k = 0; k < 64; ++k) {
        const float x = bf2f(lds1[k * 64 + t]);
        fma1<128>(x, nw2 + (size_t)k * 128, a2);
    }
#pragma unroll
    for (int j = 0; j < 128; ++j) lds2[j * 64 + t] = f2bf(siluf(a2[j]));

    // node MLP layer 3: 128 -> 128, residual (no silu)
    float a3[128];
#pragma unroll
    for (int j = 0; j < 128; ++j) a3[j] = nb3[j];
    for (int k = 0; k < 128; ++k) {
        const float x = bf2f(lds2[k * 64 + t]);
        fma1<128>(x, nw3 + (size_t)k * 128, a3);
    }
#pragma unroll
    for (int j = 0; j < 128; ++j) out_h[(size_t)n * 128 + j] = hn[j] + a3[j];

    const float invc = 1.0f / fmaxf(cnt[n], 1.0f);
#pragma unroll
    for (int d = 0; d < 3; ++d)
        out_coord[3 * n + d] = coord[3 * n + d] + agg_c[3 * n + d] * invc;
}

extern "C" void kernel_launch(void* const* d_in, const int* in_sizes, int n_in,
                              void* d_out, int out_size, void* d_ws,
                              size_t ws_size, hipStream_t stream) {
    const float* h = (const float*)d_in[0];
    const float* coord = (const float*)d_in[1];
    const float* edge_attr = (const float*)d_in[2];
    const int* row = (const int*)d_in[3];
    const int* col = (const int*)d_in[4];
    const float* ew1 = (const float*)d_in[5];
    const float* eb1 = (const float*)d_in[6];
    const float* ew2 = (const float*)d_in[7];
    const float* eb2 = (const float*)d_in[8];
    const float* ew3 = (const float*)d_in[9];
    const float* eb3 = (const float*)d_in[10];
    const float* nw1 = (const float*)d_in[11];
    const float* nb1 = (const float*)d_in[12];
    const float* nw2 = (const float*)d_in[13];
    const float* nb2 = (const float*)d_in[14];
    const float* nw3 = (const float*)d_in[15];
    const float* nb3 = (const float*)d_in[16];
    const float* cw1 = (const float*)d_in[17];
    const float* cb1 = (const float*)d_in[18];
    const float* cw2 = (const float*)d_in[19];
    const float* cb2 = (const float*)d_in[20];
    const float* cw3 = (const float*)d_in[21];

    float* ws = (float*)d_ws;
    float* agg_feat = ws;                              // N*128
    float* agg_c = ws + (size_t)NNODES * 128;          // N*3
    float* cnt = agg_c + (size_t)NNODES * 3;           // N
    hipMemsetAsync(d_ws, 0, (size_t)NNODES * 132 * sizeof(float), stream);

    edge_kernel<<<NEDGES / 64, 64, 0, stream>>>(
        h, coord, edge_attr, row, col, ew1, eb1, ew2, eb2, ew3, eb3, cw1, cb1,
        cw2, cb2, cw3, agg_feat, agg_c, cnt);

    float* out_h = (float*)d_out;
    float* out_coord = out_h + (size_t)NNODES * 128;
    float* out_ea = out_coord + (size_t)NNODES * 3;

    node_kernel<<<(NNODES + 63) / 64, 64, 0, stream>>>(
        h, coord, nw1, nb1, nw2, nb2, nw3, nb3, agg_feat, agg_c, cnt, out_h,
        out_coord);

    hipMemcpyAsync(out_ea, edge_attr, (size_t)NEDGES * 16 * sizeof(float),
                   hipMemcpyDeviceToDevice, stream);
}

// Round 2
// 500.555 us; speedup vs baseline: 5.9427x; 5.9427x over previous
//
#include <hip/hip_runtime.h>
#include <cstdint>

#define NNODES 10000
#define NEDGES 320000

typedef unsigned short u16;
typedef unsigned int u32;
typedef __attribute__((ext_vector_type(8))) short bfx8;
typedef __attribute__((ext_vector_type(8))) unsigned short u16x8;
typedef __attribute__((ext_vector_type(4))) float f32x4;

__device__ __forceinline__ float siluf(float x) {
    return __fdividef(x, 1.0f + __expf(-x));
}
__device__ __forceinline__ u16 f2bf(float x) {
    union { float f; u32 u; } v; v.f = x;
    return (u16)((v.u + 0x7FFFu + ((v.u >> 16) & 1u)) >> 16);
}
__device__ __forceinline__ float bf2f(u16 b) {
    union { u32 u; float f; } v; v.u = ((u32)b) << 16;
    return v.f;
}

// ---------------- weight transpose + bf16 convert: out[n][kpad] = in[k][n]
__global__ void convw(const float* __restrict__ in, u16* __restrict__ out,
                      int K, int N, int Kpad) {
    int idx = blockIdx.x * 256 + threadIdx.x;
    if (idx >= N * Kpad) return;
    int n = idx / Kpad, k = idx % Kpad;
    out[idx] = (k < K) ? f2bf(in[(size_t)k * N + n]) : (u16)0;
}

// ---------------- MFMA helpers ----------------
// Layouts (16x16x32 bf16): A[m][k]: m=lane&15, k=(lane>>4)*8+j
//                          B[k][n]: n=lane&15, k=(lane>>4)*8+j
//                          C/D:     col=lane&15, row=(lane>>4)*4+reg  [m89]
// LDS A-tiles swizzled: byte ^= ((m&7)<<4); row strides multiple of 128B.

template <int MT, int NT>
__device__ __forceinline__ void initAcc(f32x4 (&acc)[MT][NT],
                                        const float* __restrict__ bias,
                                        int ntBase, int lo) {
#pragma unroll
    for (int nt = 0; nt < NT; ++nt) {
        float b = bias[(ntBase + nt) * 16 + lo];
#pragma unroll
        for (int mt = 0; mt < MT; ++mt) acc[mt][nt] = (f32x4){b, b, b, b};
    }
}

template <int MT, int NT, int KC>
__device__ __forceinline__ void gemmK(f32x4 (&acc)[MT][NT],
                                      const u16* __restrict__ A, int strideB,
                                      const u16* __restrict__ Wt, int Kpad,
                                      int kGlob0, int kLoc0, int lo, int q,
                                      int ntBase) {
#pragma unroll
    for (int kc = 0; kc < KC; ++kc) {
        const int kg = kGlob0 + kc * 32 + q * 8;
        const int kl = kLoc0 + kc * 32 + q * 8;
        bfx8 bf[NT];
#pragma unroll
        for (int nt = 0; nt < NT; ++nt)
            bf[nt] = *(const bfx8*)(Wt + (size_t)((ntBase + nt) * 16 + lo) * Kpad + kg);
#pragma unroll
        for (int mt = 0; mt < MT; ++mt) {
            int m = mt * 16 + lo;
            int byte = m * strideB + kl * 2;
            byte ^= ((m & 7) << 4);
            bfx8 af = *(const bfx8*)((const char*)A + byte);
#pragma unroll
            for (int nt = 0; nt < NT; ++nt)
                acc[mt][nt] = __builtin_amdgcn_mfma_f32_16x16x32_bf16(
                    af, bf[nt], acc[mt][nt], 0, 0, 0);
        }
    }
}

template <int MT, int NT>
__device__ __forceinline__ void writeAct(u16* dst, int strideB,
                                         const f32x4 (&acc)[MT][NT], int lo,
                                         int q, int ntBase) {
#pragma unroll
    for (int mt = 0; mt < MT; ++mt)
#pragma unroll
        for (int nt = 0; nt < NT; ++nt)
#pragma unroll
            for (int rr = 0; rr < 4; ++rr) {
                int m = mt * 16 + q * 4 + rr;
                int n = (ntBase + nt) * 16 + lo;
                int byte = m * strideB + n * 2;
                byte ^= ((m & 7) << 4);
                *(u16*)((char*)dst + byte) = f2bf(siluf(acc[mt][nt][rr]));
            }
}

// stage 8 bf16 cols for edge e at global-k kg (multiple of 8) into swizzled LDS
__device__ __forceinline__ void stageGroups(u16* buf, const float* __restrict__ h,
                                            const float* __restrict__ ea, int ge,
                                            int r, int c, float radial, int e,
                                            int p, int kBase, int nGroups) {
    for (int g = 0; g < nGroups; ++g) {
        int kg = kBase + (p * nGroups + g) * 8;
        float4 lov, hiv;
        if (kg < 128) {
            const float* s = h + (size_t)r * 128 + kg;
            lov = *(const float4*)s; hiv = *(const float4*)(s + 4);
        } else if (kg < 256) {
            const float* s = h + (size_t)c * 128 + (kg - 128);
            lov = *(const float4*)s; hiv = *(const float4*)(s + 4);
        } else if (kg < 272) {
            const float* s = ea + (size_t)ge * 16 + (kg - 256);
            lov = *(const float4*)s; hiv = *(const float4*)(s + 4);
        } else if (kg == 272) {
            lov = make_float4(radial, 0.f, 0.f, 0.f);
            hiv = make_float4(0.f, 0.f, 0.f, 0.f);
        } else {
            lov = make_float4(0.f, 0.f, 0.f, 0.f);
            hiv = make_float4(0.f, 0.f, 0.f, 0.f);
        }
        int kl = kg - kBase;
        u16x8 v;
        v[0] = f2bf(lov.x); v[1] = f2bf(lov.y); v[2] = f2bf(lov.z); v[3] = f2bf(lov.w);
        v[4] = f2bf(hiv.x); v[5] = f2bf(hiv.y); v[6] = f2bf(hiv.z); v[7] = f2bf(hiv.w);
        int byte = e * 384 + kl * 2;
        byte ^= ((e & 7) << 4);
        *(u16x8*)((char*)buf + byte) = v;
    }
}

// ---------------- fused edge kernel: 1 block = 4 waves = 64 edges ----------------
__global__ __launch_bounds__(256, 3)
void edge_mfma(const float* __restrict__ h, const float* __restrict__ coord,
               const float* __restrict__ edge_attr, const int* __restrict__ row,
               const int* __restrict__ col, const u16* __restrict__ wbf,
               const float* __restrict__ eb1, const float* __restrict__ eb2,
               const float* __restrict__ eb3, const float* __restrict__ cb1,
               const float* __restrict__ cb2, const float* __restrict__ cw3,
               float* __restrict__ agg_feat, float* __restrict__ agg_c,
               float* __restrict__ cnt) {
    // reg0: A1 staging [64][192-stride] (2-pass K), later act2 [64][128]
    // reg1: act1 [64][64], later cact1 [64][64]
    // reg2: edge_feat [64][128]
    __shared__ __attribute__((aligned(16))) u16 reg0[64 * 192];
    __shared__ __attribute__((aligned(16))) u16 reg1[64 * 64];
    __shared__ __attribute__((aligned(16))) u16 reg2[64 * 128];
    __shared__ int srow[64];
    __shared__ float sxyz[64][3];
    __shared__ float red[64][4];

    const u16* ew1t = wbf;             // [64][288]
    const u16* ew2t = wbf + 18432;     // [128][64]
    const u16* ew3t = wbf + 26624;     // [128][128]
    const u16* cw1t = wbf + 43008;     // [64][128]
    const u16* cw2t = wbf + 51200;     // [128][64]

    const int t = threadIdx.x;
    const int w = t >> 6, l = t & 63, lo = l & 15, q = l >> 4;
    const int eb = blockIdx.x * 64;
    const int e = t >> 2, p = t & 3, ge = eb + e;
    const int r = row[ge], c = col[ge];
    if (p == 0) srow[e] = r;
    if (p == 1) {
        float dx = coord[3 * r + 0] - coord[3 * c + 0];
        float dy = coord[3 * r + 1] - coord[3 * c + 1];
        float dz = coord[3 * r + 2] - coord[3 * c + 2];
        sxyz[e][0] = dx; sxyz[e][1] = dy; sxyz[e][2] = dz;
    }
    // ---- stage A1 pass 1: k in [0,192)
    stageGroups(reg0, h, edge_attr, ge, r, c, 0.0f, e, p, 0, 6);
    f32x4 acc1[4][1];
    initAcc<4, 1>(acc1, eb1, w, lo);
    __syncthreads();
    // ---- L1 (273->64) part 1: 6 K-chunks
    gemmK<4, 1, 6>(acc1, reg0, 384, ew1t, 288, 0, 0, lo, q, w);
    __syncthreads();
    // ---- stage A1 pass 2: k in [192,288) (incl. radial at 272, zero pad)
    float radial = sxyz[e][0] * sxyz[e][0] + sxyz[e][1] * sxyz[e][1] +
                   sxyz[e][2] * sxyz[e][2];
    stageGroups(reg0, h, edge_attr, ge, r, c, radial, e, p, 192, 3);
    __syncthreads();
    gemmK<4, 1, 3>(acc1, reg0, 384, ew1t, 288, 192, 0, lo, q, w);
    writeAct<4, 1>(reg1, 128, acc1, lo, q, w);
    __syncthreads();
    // ---- L2 (64->128)
    f32x4 acc2[4][2];
    initAcc<4, 2>(acc2, eb2, 2 * w, lo);
    gemmK<4, 2, 2>(acc2, reg1, 128, ew2t, 64, 0, 0, lo, q, 2 * w);
    writeAct<4, 2>(reg0, 256, acc2, lo, q, 2 * w);
    __syncthreads();
    // ---- L3 (128->128) -> edge_feat; LDS store + coalesced atomic agg
    f32x4 acc3[4][2];
    initAcc<4, 2>(acc3, eb3, 2 * w, lo);
    gemmK<4, 2, 4>(acc3, reg0, 256, ew3t, 128, 0, 0, lo, q, 2 * w);
#pragma unroll
    for (int mt = 0; mt < 4; ++mt) {
#pragma unroll
        for (int rr = 0; rr < 4; ++rr) {
            int m = mt * 16 + q * 4 + rr;
            int nr = srow[m];
#pragma unroll
            for (int nt = 0; nt < 2; ++nt) {
                int n = (2 * w + nt) * 16 + lo;
                float v = siluf(acc3[mt][nt][rr]);
                int byte = m * 256 + n * 2;
                byte ^= ((m & 7) << 4);
                *(u16*)((char*)reg2 + byte) = f2bf(v);
                unsafeAtomicAdd(agg_feat + (size_t)nr * 128 + n, v);
            }
        }
    }
    __syncthreads();
    // ---- C1 (128->64)
    f32x4 acc4[4][1];
    initAcc<4, 1>(acc4, cb1, w, lo);
    gemmK<4, 1, 4>(acc4, reg2, 256, cw1t, 128, 0, 0, lo, q, w);
    writeAct<4, 1>(reg1, 128, acc4, lo, q, w);
    __syncthreads();
    // ---- C2 (64->128) fused with cw3 dot
    f32x4 acc5[4][2];
    initAcc<4, 2>(acc5, cb2, 2 * w, lo);
    gemmK<4, 2, 2>(acc5, reg1, 128, cw2t, 64, 0, 0, lo, q, 2 * w);
    float w3a = cw3[(2 * w) * 16 + lo], w3b = cw3[(2 * w + 1) * 16 + lo];
#pragma unroll
    for (int mt = 0; mt < 4; ++mt) {
#pragma unroll
        for (int rr = 0; rr < 4; ++rr) {
            float v = siluf(acc5[mt][0][rr]) * w3a + siluf(acc5[mt][1][rr]) * w3b;
            v += __shfl_xor(v, 1);
            v += __shfl_xor(v, 2);
            v += __shfl_xor(v, 4);
            v += __shfl_xor(v, 8);
            if (lo == 0) red[mt * 16 + q * 4 + rr][w] = v;
        }
    }
    __syncthreads();
    if (t < 64) {
        float cv = red[t][0] + red[t][1] + red[t][2] + red[t][3];
        int nr = srow[t];
        float dx = sxyz[t][0], dy = sxyz[t][1], dz = sxyz[t][2];
        float tx = fminf(fmaxf(dx * cv, -100.f), 100.f);
        float ty = fminf(fmaxf(dy * cv, -100.f), 100.f);
        float tz = fminf(fmaxf(dz * cv, -100.f), 100.f);
        unsafeAtomicAdd(agg_c + 3 * nr + 0, tx);
        unsafeAtomicAdd(agg_c + 3 * nr + 1, ty);
        unsafeAtomicAdd(agg_c + 3 * nr + 2, tz);
        unsafeAtomicAdd(cnt + nr, 1.0f);
    }
}

// ---------------- node kernel (unchanged from round 0, passes) ----------------
template <int JN>
__device__ __forceinline__ void fma4(const float4 x, const float* __restrict__ w,
                                     float* acc) {
#pragma unroll
    for (int j = 0; j < JN; ++j) {
        float s = fmaf(x.x, w[j], acc[j]);
        s = fmaf(x.y, w[JN + j], s);
        s = fmaf(x.z, w[2 * JN + j], s);
        acc[j] = fmaf(x.w, w[3 * JN + j], s);
    }
}
template <int JN>
__device__ __forceinline__ void fma1(const float x, const float* __restrict__ w,
                                     float* acc) {
#pragma unroll
    for (int j = 0; j < JN; ++j) acc[j] = fmaf(x, w[j], acc[j]);
}

__global__ __launch_bounds__(64, 2)
void node_kernel(const float* __restrict__ h, const float* __restrict__ coord,
                 const float* __restrict__ nw1, const float* __restrict__ nb1,
                 const float* __restrict__ nw2, const float* __restrict__ nb2,
                 const float* __restrict__ nw3, const float* __restrict__ nb3,
                 const float* __restrict__ agg_feat,
                 const float* __restrict__ agg_c, const float* __restrict__ cnt,
                 float* __restrict__ out_h, float* __restrict__ out_coord) {
    __shared__ u16 lds1[64 * 64];
    __shared__ u16 lds2[128 * 64];
    const int t = threadIdx.x;
    const int n = blockIdx.x * 64 + t;
    if (n >= NNODES) return;
    const float* hn = h + (size_t)n * 128;
    const float* an = agg_feat + (size_t)n * 128;

    float a1[64];
#pragma unroll
    for (int j = 0; j < 64; ++j) a1[j] = nb1[j];
    for (int k = 0; k < 128; k += 4) {
        const float4 x = *(const float4*)(hn + k);
        fma4<64>(x, nw1 + (size_t)k * 64, a1);
    }
    for (int k = 0; k < 128; k += 4) {
        const float4 x = *(const float4*)(an + k);
        fma4<64>(x, nw1 + (size_t)(128 + k) * 64, a1);
    }
#pragma unroll
    for (int j = 0; j < 64; ++j) lds1[j * 64 + t] = f2bf(siluf(a1[j]));

    float a2[128];
#pragma unroll
    for (int j = 0; j < 128; ++j) a2[j] = nb2[j];
    for (int k = 0; k < 64; ++k) {
        const float x = bf2f(lds1[k * 64 + t]);
        fma1<128>(x, nw2 + (size_t)k * 128, a2);
    }
#pragma unroll
    for (int j = 0; j < 128; ++j) lds2[j * 64 + t] = f2bf(siluf(a2[j]));

    float a3[128];
#pragma unroll
    for (int j = 0; j < 128; ++j) a3[j] = nb3[j];
    for (int k = 0; k < 128; ++k) {
        const float x = bf2f(lds2[k * 64 + t]);
        fma1<128>(x, nw3 + (size_t)k * 128, a3);
    }
#pragma unroll
    for (int j = 0; j < 128; ++j) out_h[(size_t)n * 128 + j] = hn[j] + a3[j];

    const float invc = 1.0f / fmaxf(cnt[n], 1.0f);
#pragma unroll
    for (int d = 0; d < 3; ++d)
        out_coord[3 * n + d] = coord[3 * n + d] + agg_c[3 * n + d] * invc;
}

extern "C" void kernel_launch(void* const* d_in, const int* in_sizes, int n_in,
                              void* d_out, int out_size, void* d_ws,
                              size_t ws_size, hipStream_t stream) {
    const float* h = (const float*)d_in[0];
    const float* coord = (const float*)d_in[1];
    const float* edge_attr = (const float*)d_in[2];
    const int* row = (const int*)d_in[3];
    const int* col = (const int*)d_in[4];
    const float* ew1 = (const float*)d_in[5];
    const float* eb1 = (const float*)d_in[6];
    const float* ew2 = (const float*)d_in[7];
    const float* eb2 = (const float*)d_in[8];
    const float* ew3 = (const float*)d_in[9];
    const float* eb3 = (const float*)d_in[10];
    const float* nw1 = (const float*)d_in[11];
    const float* nb1 = (const float*)d_in[12];
    const float* nw2 = (const float*)d_in[13];
    const float* nb2 = (const float*)d_in[14];
    const float* nw3 = (const float*)d_in[15];
    const float* nb3 = (const float*)d_in[16];
    const float* cw1 = (const float*)d_in[17];
    const float* cb1 = (const float*)d_in[18];
    const float* cw2 = (const float*)d_in[19];
    const float* cb2 = (const float*)d_in[20];
    const float* cw3 = (const float*)d_in[21];

    float* ws = (float*)d_ws;
    float* agg_feat = ws;                       // N*128
    float* agg_c = ws + 1280000;                // N*3
    float* cnt = ws + 1310000;                  // N
    u16* wbf = (u16*)(ws + 1320000);            // bf16 transposed weights
    hipMemsetAsync(d_ws, 0, 1320000 * sizeof(float), stream);

    convw<<<(64 * 288 + 255) / 256, 256, 0, stream>>>(ew1, wbf, 273, 64, 288);
    convw<<<(128 * 64 + 255) / 256, 256, 0, stream>>>(ew2, wbf + 18432, 64, 128, 64);
    convw<<<(128 * 128 + 255) / 256, 256, 0, stream>>>(ew3, wbf + 26624, 128, 128, 128);
    convw<<<(64 * 128 + 255) / 256, 256, 0, stream>>>(cw1, wbf + 43008, 128, 64, 128);
    convw<<<(128 * 64 + 255) / 256, 256, 0, stream>>>(cw2, wbf + 51200, 64, 128, 64);

    edge_mfma<<<NEDGES / 64, 256, 0, stream>>>(
        h, coord, edge_attr, row, col, wbf, eb1, eb2, eb3, cb1, cb2, cw3,
        agg_feat, agg_c, cnt);

    float* out_h = (float*)d_out;
    float* out_coord = out_h + (size_t)NNODES * 128;
    float* out_ea = out_coord + (size_t)NNODES * 3;

    node_kernel<<<(NNODES + 63) / 64, 64, 0, stream>>>(
        h, coord, nw1, nb1, nw2, nb2, nw3, nb3, agg_feat, agg_c, cnt, out_h,
        out_coord);

    hipMemcpyAsync(out_ea, edge_attr, (size_t)NEDGES * 16 * sizeof(float),
                   hipMemcpyDeviceToDevice, stream);
}